// Round 7
// baseline (50.118 us; speedup 1.0000x reference)
//
#include <hip/hip_runtime.h>
#include <hip/hip_bf16.h>

// Bundle-adjustment residual — single-kernel version.
// R7: collapse to ONE dispatch for profile visibility + overhead removal.
//  - poses (112 KB) staged to LDS via coalesced linear float4 copy,
//    row-major stride 7 dwords (coprime with 32 banks for random-row reads);
//    quaternion normalized per-use (VALU has headroom).
//  - patch gathered directly from raw patch_coords (float2) + elev (float):
//    no pack kernel, no workspace.
//  - ALL loads/stores plain (R2's non-temporal hints coincided with a
//    slowdown vs naive R1 — this round A/Bs NT away).
//  - 8 obs/thread in 2 groups of 4 (register-friendly), 1024 thr/block,
//    grid=256 -> one block per CU, single staging phase.

#define NPOSES      4096
#define POSE_DWORDS (NPOSES * 7)          // 28672 dwords = 112 KB
#define POSE_VEC4   (POSE_DWORDS / 4)     // 7168 float4

typedef float fvec4 __attribute__((ext_vector_type(4)));
typedef int   ivec4 __attribute__((ext_vector_type(4)));

__global__ __launch_bounds__(1024) void ba_one_kernel(
    const float* __restrict__ poses,         // [4096,7]
    const float* __restrict__ patch_coords,  // [NPATCHES,2]
    const float* __restrict__ elev,          // [NPATCHES,1]
    const int*   __restrict__ poses_idx,     // [NOBS]
    const int*   __restrict__ patch_idx,     // [NOBS]
    const float* __restrict__ target,        // [NOBS,3]
    const float* __restrict__ weights,       // [NOBS,1]
    float*       __restrict__ out,           // [NOBS,3]
    int n8)                                  // NOBS/8
{
    extern __shared__ float lds[];           // 112 KB of poses
    int tid = threadIdx.x;

    // Coalesced linear staging: 7168 float4 / 1024 threads = 7 each.
    {
        const fvec4* src = reinterpret_cast<const fvec4*>(poses);
        fvec4* dst = reinterpret_cast<fvec4*>(lds);
#pragma unroll
        for (int j = 0; j < POSE_VEC4 / 1024; ++j)
            dst[tid + j * 1024] = src[tid + j * 1024];
    }
    __syncthreads();

    int i8 = blockIdx.x * blockDim.x + tid;
    if (i8 >= n8) return;

    const ivec4* pi4 = reinterpret_cast<const ivec4*>(poses_idx);
    const ivec4* qi4 = reinterpret_cast<const ivec4*>(patch_idx);
    const fvec4* w4p = reinterpret_cast<const fvec4*>(weights);
    const fvec4* tg4 = reinterpret_cast<const fvec4*>(target) + (size_t)i8 * 6;
    fvec4*       o4  = reinterpret_cast<fvec4*>(out) + (size_t)i8 * 6;

#pragma unroll
    for (int g = 0; g < 2; ++g) {
        ivec4 pidx = pi4[(size_t)i8 * 2 + g];
        ivec4 qidx = qi4[(size_t)i8 * 2 + g];
        fvec4 w4   = w4p[(size_t)i8 * 2 + g];
        fvec4 t0 = tg4[g * 3 + 0];
        fvec4 t1 = tg4[g * 3 + 1];
        fvec4 t2 = tg4[g * 3 + 2];

        int   pi[4] = {pidx.x, pidx.y, pidx.z, pidx.w};
        int   qi[4] = {qidx.x, qidx.y, qidx.z, qidx.w};
        float ww[4] = {w4.x, w4.y, w4.z, w4.w};
        float tg[12] = {t0.x, t0.y, t0.z, t0.w,
                        t1.x, t1.y, t1.z, t1.w,
                        t2.x, t2.y, t2.z, t2.w};

        float res[12];

#pragma unroll
        for (int k = 0; k < 4; ++k) {
            // Pose from LDS (7 dwords, stride-7 rows spread over 32 banks).
            const float* pl = lds + pi[k] * 7;
            float tx = pl[0], ty = pl[1], tz = pl[2];
            float qx = pl[3], qy = pl[4], qz = pl[5], qw = pl[6];
            float inv = rsqrtf(qx*qx + qy*qy + qz*qz + qw*qw);
            qx *= inv; qy *= inv; qz *= inv; qw *= inv;

            // Patch gather: float2 + float, L2-resident (3 MB total).
            float2 pc = *reinterpret_cast<const float2*>(patch_coords + (size_t)qi[k] * 2);
            float px = pc.x, py = pc.y, pz = elev[qi[k]];

            // uv = cross(qv, pts)
            float ux = qy*pz - qz*py;
            float uy = qz*px - qx*pz;
            float uz = qx*py - qy*px;
            // cross(qv, uv)
            float cx = qy*uz - qz*uy;
            float cy = qz*ux - qx*uz;
            float cz = qx*uy - qy*ux;
            // rotated = pts + 2*(qw*uv + cross(qv,uv)) + t
            float rx = px + 2.0f*(qw*ux + cx) + tx;
            float ry = py + 2.0f*(qw*uy + cy) + ty;
            float rz = pz + 2.0f*(qw*uz + cz) + tz;

            // cart2polar (matches reference)
            float rho = sqrtf(rx*rx + ry*ry);
            float r   = sqrtf(rho*rho + rz*rz);
            float az  = atan2f(ry, rx);
            float el  = atan2f(rz, rho);

            res[k*3 + 0] = (r  - tg[k*3 + 0]) * ww[k];
            res[k*3 + 1] = (az - tg[k*3 + 1]) * ww[k];
            res[k*3 + 2] = (el - tg[k*3 + 2]) * ww[k];
        }

        o4[g * 3 + 0] = (fvec4){res[0], res[1], res[2],  res[3]};
        o4[g * 3 + 1] = (fvec4){res[4], res[5], res[6],  res[7]};
        o4[g * 3 + 2] = (fvec4){res[8], res[9], res[10], res[11]};
    }
}

// Fallback path: direct global gathers (no LDS attribute needed).
__global__ __launch_bounds__(256) void ba_fallback_kernel(
    const float* __restrict__ poses, const float* __restrict__ patch_coords,
    const float* __restrict__ elev, const int* __restrict__ poses_idx,
    const int* __restrict__ patch_idx, const float* __restrict__ target,
    const float* __restrict__ weights, float* __restrict__ out, int n)
{
    int i = blockIdx.x * blockDim.x + threadIdx.x;
    if (i >= n) return;
    int pi = poses_idx[i];
    int qi = patch_idx[i];
    const float* p = poses + (size_t)pi * 7;
    float tx = p[0], ty = p[1], tz = p[2];
    float qx = p[3], qy = p[4], qz = p[5], qw = p[6];
    float inv = rsqrtf(qx*qx + qy*qy + qz*qz + qw*qw);
    qx *= inv; qy *= inv; qz *= inv; qw *= inv;
    float2 pc = *reinterpret_cast<const float2*>(patch_coords + (size_t)qi * 2);
    float px = pc.x, py = pc.y, pz = elev[qi];
    float ux = qy*pz - qz*py, uy = qz*px - qx*pz, uz = qx*py - qy*px;
    float cx = qy*uz - qz*uy, cy = qz*ux - qx*uz, cz = qx*uy - qy*ux;
    float rx = px + 2.0f*(qw*ux + cx) + tx;
    float ry = py + 2.0f*(qw*uy + cy) + ty;
    float rz = pz + 2.0f*(qw*uz + cz) + tz;
    float rho = sqrtf(rx*rx + ry*ry);
    float r   = sqrtf(rho*rho + rz*rz);
    float az  = atan2f(ry, rx);
    float el  = atan2f(rz, rho);
    float w = weights[i];
    out[(size_t)i*3+0] = (r  - target[(size_t)i*3+0]) * w;
    out[(size_t)i*3+1] = (az - target[(size_t)i*3+1]) * w;
    out[(size_t)i*3+2] = (el - target[(size_t)i*3+2]) * w;
}

extern "C" void kernel_launch(void* const* d_in, const int* in_sizes, int n_in,
                              void* d_out, int out_size, void* d_ws, size_t ws_size,
                              hipStream_t stream) {
    const float* poses        = (const float*)d_in[0];
    const float* patch_coords = (const float*)d_in[1];
    const float* elev         = (const float*)d_in[2];
    const int*   poses_idx    = (const int*)d_in[3];
    const int*   patch_idx    = (const int*)d_in[4];
    const float* target       = (const float*)d_in[5];
    const float* weights      = (const float*)d_in[6];
    float*       out          = (float*)d_out;

    int n  = in_sizes[3];  // NUM_OBS (2097152, divisible by 8)
    int n8 = n / 8;

    size_t lds_bytes = (size_t)POSE_DWORDS * 4;  // 114688 B

    hipError_t attr_err = hipFuncSetAttribute(
        reinterpret_cast<const void*>(ba_one_kernel),
        hipFuncAttributeMaxDynamicSharedMemorySize, (int)lds_bytes);

    if (attr_err == hipSuccess) {
        int block = 1024;
        int grid  = (n8 + block - 1) / block;  // 256 = one block per CU
        ba_one_kernel<<<grid, block, lds_bytes, stream>>>(
            poses, patch_coords, elev, poses_idx, patch_idx,
            target, weights, out, n8);
    } else {
        ba_fallback_kernel<<<(n + 255) / 256, 256, 0, stream>>>(
            poses, patch_coords, elev, poses_idx, patch_idx, target, weights, out, n);
    }
}